// Round 8
// baseline (579.576 us; speedup 1.0000x reference)
//
#include <hip/hip_runtime.h>

// ---------------------------------------------------------------------------
// TopKPooling (PyG-style) on MI355X.
// score = tanh((x @ w) / ||w||)  [XLA EmitTanh f32 replica — DO NOT TOUCH,
//                                 bit-exactness validated in round 1]
// Stable LSD radix sort, round-3 dense-scan structure (global sync via
// kernel boundaries — both lookback (r5) and wait-all (r6/7) measured
// slower due to agent-scope atomic traffic bypassing per-XCD L2).
// Next-pass per-block histogram fused into scatter via global atomics;
// select fused into final scatter. 11 dispatches total.
// Edge relabel: two-phase 64KB LDS bitmap probe + conditional ni gather
// (validated round 3; untouched).
// ---------------------------------------------------------------------------

#define N_NODES 1000000
#define N_EDGES 16000000
#define K_SEL   500000

typedef int      v4i __attribute__((ext_vector_type(4)));
typedef float    v4f __attribute__((ext_vector_type(4)));
typedef unsigned v4u __attribute__((ext_vector_type(4)));
typedef unsigned long long u64;

static constexpr int NDIG     = 256;
static constexpr int STHREADS = 256;                 // 4 waves
static constexpr int SIPT     = 8;
static constexpr int SCHUNK   = STHREADS * SIPT;     // 2048
static constexpr int NB       = (N_NODES + SCHUNK - 1) / SCHUNK;  // 489
static constexpr int NWAVE    = STHREADS / 64;
static constexpr int LOG_SCHUNK = 11;

static constexpr int EB_THREADS = 1024;
static constexpr int EB_EDGES   = EB_THREADS * 8;    // 8192
static constexpr int NODE_SPLIT = 524288;            // word-aligned split
static constexpr int BM_WORDS   = (N_NODES + 31) / 32;   // 31250
static constexpr int BM_W0      = NODE_SPLIT / 32;       // 16384 (64 KiB)
static constexpr int BM_W1      = BM_WORDS - BM_W0;      // 14866
static constexpr int BM_ALLOC   = 31264;                 // padded to x4

// --- XLA EmitTanh f32 replica (elemental_ir_emitter). No FMA contraction. ---
__device__ __forceinline__ float tanh_xla(float x) {
  const float kCutoff = 0.0004f;
  const float kClamp  = 7.90531110763549805f;
  float ax = fabsf(x);
  float xc = fminf(fmaxf(x, -kClamp), kClamp);
  float x2 = __fmul_rn(xc, xc);
  float p = -2.76076847742355e-16f;
  p = __fadd_rn(__fmul_rn(p, x2),  2.00018790482477e-13f);
  p = __fadd_rn(__fmul_rn(p, x2), -8.60467152213735e-11f);
  p = __fadd_rn(__fmul_rn(p, x2),  5.12229709037114e-08f);
  p = __fadd_rn(__fmul_rn(p, x2),  1.48572235717979e-05f);
  p = __fadd_rn(__fmul_rn(p, x2),  6.37261928875436e-04f);
  p = __fadd_rn(__fmul_rn(p, x2),  4.89352455891786e-03f);
  float num = __fmul_rn(xc, p);
  float q = 1.19825839466702e-06f;
  q = __fadd_rn(__fmul_rn(q, x2), 1.18534705686654e-04f);
  q = __fadd_rn(__fmul_rn(q, x2), 2.26843463243900e-03f);
  q = __fadd_rn(__fmul_rn(q, x2), 4.89352518554385e-03f);
  float r = __fdiv_rn(num, q);
  return (ax < kCutoff) ? x : r;
}

// ---- zero {bm | histDM passes 1..3} with one uint4 per thread ----
__global__ __launch_bounds__(256) void zero_meta(v4u* __restrict__ p, int n4) {
  int i = blockIdx.x * 256 + threadIdx.x;
  if (i < n4) p[i] = v4u{0u, 0u, 0u, 0u};
}

// ---- score + packed keys + exact pass-0 per-block histogram ----
__global__ __launch_bounds__(STHREADS) void score_pass(
    const float* __restrict__ x, const float* __restrict__ w,
    u64* __restrict__ kp0, unsigned* __restrict__ histDM0) {
  __shared__ unsigned h[NDIG];
  const int t = threadIdx.x, b = blockIdx.x;
  const int base = b * SCHUNK;
  h[t] = 0;
  __syncthreads();
  float w0 = w[0], w1 = w[1], w2 = w[2];
  float nrm = __fsqrt_rn(__fadd_rn(__fadd_rn(__fmul_rn(w0, w0), __fmul_rn(w1, w1)),
                                   __fmul_rn(w2, w2)));
#pragma unroll
  for (int s = 0; s < SIPT; ++s) {
    int i = base + s * STHREADS + t;
    if (i < N_NODES) {
      float dot = __fadd_rn(__fadd_rn(__fmul_rn(x[3*i+0], w0), __fmul_rn(x[3*i+1], w1)),
                            __fmul_rn(x[3*i+2], w2));
      float z = __fdiv_rn(dot, nrm);
      float sc = tanh_xla(z);
      unsigned u = __float_as_uint(sc);
      if (u == 0x80000000u) u = 0u;                    // -0 == +0
      u = (u & 0x80000000u) ? ~u : (u | 0x80000000u);  // ascending map
      unsigned key = ~u;                               // descending score
      kp0[i] = ((u64)key << 32) | (unsigned)i;
      atomicAdd(&h[key & 255u], 1u);
    }
  }
  __syncthreads();
  histDM0[t * NB + b] = h[t];
}

// ---- exclusive scan of each digit row (NB entries); rowsum[d] = total ----
__global__ void scan_rows(unsigned* __restrict__ histDM, unsigned* __restrict__ rowsum) {
  __shared__ unsigned lds[512];
  int d = blockIdx.x, t = threadIdx.x;
  unsigned v = (t < NB) ? histDM[d * NB + t] : 0u;
  lds[t] = v;
  __syncthreads();
#pragma unroll
  for (int off = 1; off < 512; off <<= 1) {
    unsigned add = (t >= off) ? lds[t - off] : 0u;
    __syncthreads();
    lds[t] += add;
    __syncthreads();
  }
  if (t < NB) histDM[d * NB + t] = lds[t] - v;
  if (t == 511) rowsum[d] = lds[511];
}

// ---- stable scatter (r3-validated core): ballot ranks + LDS reorder.
// Extras: next-pass per-block histogram via global atomics (PASS<3);
// PASS==3 fused with select (ni/bm/xout written directly).
template <int PASS>
__global__ __launch_bounds__(STHREADS) void scatter_pass(
    const u64* __restrict__ kin, u64* __restrict__ kout,
    const unsigned* __restrict__ histDM, const unsigned* __restrict__ rowsum,
    unsigned* __restrict__ histNext,
    const float* __restrict__ x, int* __restrict__ ni,
    unsigned* __restrict__ bm, float* __restrict__ xout) {
  constexpr bool FINAL = (PASS == 3);
  __shared__ unsigned short whist[SIPT][NWAVE][NDIG];  // 16 KiB
  __shared__ unsigned goff[NDIG];
  __shared__ unsigned bexcl[NDIG];
  __shared__ unsigned scanbuf[NDIG];
  __shared__ u64 lkp[FINAL ? 1 : SCHUNK];              // 16 KiB (non-final)
  const int t = threadIdx.x, b = blockIdx.x;
  const int wave = t >> 6, lane = t & 63;
  const int base = b * SCHUNK;
  const int sh = 32 + 8 * PASS;

  for (int j = t; j < SIPT * NWAVE * NDIG; j += STHREADS)
    ((unsigned short*)whist)[j] = 0;
  // rowbase = exclusive scan of rowsum (256 entries, folded per block — r3)
  unsigned rs = rowsum[t];
  scanbuf[t] = rs;
  __syncthreads();
#pragma unroll
  for (int o = 1; o < NDIG; o <<= 1) {
    unsigned add = (t >= o) ? scanbuf[t - o] : 0u;
    __syncthreads();
    scanbuf[t] += add;
    __syncthreads();
  }
  goff[t] = (scanbuf[t] - rs) + histDM[t * NB + b];
  __syncthreads();

  u64 k[SIPT];
  unsigned dg[SIPT], lr[SIPT];
  bool val[SIPT];
#pragma unroll
  for (int s = 0; s < SIPT; ++s) {
    int i = base + s * STHREADS + t;
    val[s] = (i < N_NODES);
    k[s] = val[s] ? kin[i] : 0ull;
    dg[s] = (unsigned)(k[s] >> sh) & 255u;
  }
#pragma unroll
  for (int s = 0; s < SIPT; ++s) {
    unsigned long long m = ~0ull;
#pragma unroll
    for (int bb = 0; bb < 8; ++bb) {
      unsigned long long vote = __ballot((dg[s] >> bb) & 1u);
      m &= ((dg[s] >> bb) & 1u) ? vote : ~vote;
    }
    m &= __ballot(val[s]);
    lr[s] = (unsigned)__popcll(m & ((1ull << lane) - 1ull));
    if (val[s] && lr[s] == 0)  // leader: lowest valid lane of its digit group
      whist[s][wave][dg[s]] = (unsigned short)__popcll(m);
  }
  __syncthreads();
  // per-digit serial scan over (s,wave) in item order; run = block digit count
  unsigned run = 0;
#pragma unroll
  for (int s = 0; s < SIPT; ++s)
#pragma unroll
    for (int wv = 0; wv < NWAVE; ++wv) {
      unsigned c = whist[s][wv][t];
      whist[s][wv][t] = (unsigned short)run;
      run += c;
    }
  scanbuf[t] = run;
  __syncthreads();
#pragma unroll
  for (int o = 1; o < NDIG; o <<= 1) {
    unsigned add = (t >= o) ? scanbuf[t - o] : 0u;
    __syncthreads();
    scanbuf[t] += add;
    __syncthreads();
  }
  bexcl[t] = scanbuf[t] - run;
  __syncthreads();

  if constexpr (!FINAL) {
    // local counting-sort reorder into LDS
#pragma unroll
    for (int s = 0; s < SIPT; ++s)
      if (val[s]) {
        unsigned lp = bexcl[dg[s]] + (unsigned)whist[s][wave][dg[s]] + lr[s];
        lkp[lp] = k[s];
      }
    __syncthreads();
    // contiguous LDS read -> digit-run-coalesced global write + next-hist
    int nvalid = min(N_NODES - base, SCHUNK);
#pragma unroll
    for (int s = 0; s < SIPT; ++s) {
      int j = s * STHREADS + t;
      if (j < nvalid) {
        u64 kk = lkp[j];
        unsigned d = (unsigned)(kk >> sh) & 255u;
        unsigned gpos = goff[d] + ((unsigned)j - bexcl[d]);
        kout[gpos] = kk;
        unsigned d2 = (unsigned)(kk >> (sh + 8)) & 255u;
        atomicAdd(&histNext[d2 * NB + (gpos >> LOG_SCHUNK)], 1u);
      }
    }
  } else {
    // fused select: position < K_SEL -> emit ni/bm/xout directly
#pragma unroll
    for (int s = 0; s < SIPT; ++s) {
      if (val[s]) {
        unsigned gpos = goff[dg[s]] + (unsigned)whist[s][wave][dg[s]] + lr[s];
        if (gpos < K_SEL) {
          int idx = (int)(unsigned)(k[s] & 0xFFFFFFFFull);
          ni[idx] = (int)gpos;
          atomicOr(&bm[idx >> 5], 1u << (idx & 31));
          unsigned uo = ~(unsigned)(k[s] >> 32);          // invert key bijection
          unsigned bits = (uo & 0x80000000u) ? (uo ^ 0x80000000u) : ~uo;
          float sc = __uint_as_float(bits);
          xout[3*gpos+0] = __fmul_rn(x[3*idx+0], sc);
          xout[3*gpos+1] = __fmul_rn(x[3*idx+1], sc);
          xout[3*gpos+2] = __fmul_rn(x[3*idx+2], sc);
        }
      }
    }
  }
}

// ---- edge relabel: two-phase 64KB LDS bitmap (validated round 3) ----
__global__ __launch_bounds__(EB_THREADS) void edge_kernel(
    const int* __restrict__ ei, const int* __restrict__ ni,
    const unsigned* __restrict__ bm,
    float* __restrict__ oedge, float* __restrict__ omask) {
  __shared__ unsigned lbm[BM_W0];  // 64 KiB
  int t = threadIdx.x;
  long long e = (long long)blockIdx.x * EB_EDGES + (long long)t * 8;
  bool act = (e + 8 <= (long long)N_EDGES);

  v4i a0{}, a1{}, b0{}, b1{};
  if (act) {
    a0 = __builtin_nontemporal_load((const v4i*)(ei + e));
    a1 = __builtin_nontemporal_load((const v4i*)(ei + e) + 1);
    b0 = __builtin_nontemporal_load((const v4i*)(ei + (long long)N_EDGES + e));
    b1 = __builtin_nontemporal_load((const v4i*)(ei + (long long)N_EDGES + e) + 1);
  }
  int A[8], B[8];
#pragma unroll
  for (int j = 0; j < 4; ++j) {
    A[j] = a0[j]; A[4 + j] = a1[j];
    B[j] = b0[j]; B[4 + j] = b1[j];
  }
#pragma unroll
  for (int j = 0; j < BM_W0 / (EB_THREADS * 4); ++j)
    ((v4u*)lbm)[t + j * EB_THREADS] = ((const v4u*)bm)[t + j * EB_THREADS];
  __syncthreads();
  unsigned bA = 0, bB = 0;
  if (act) {
#pragma unroll
    for (int j = 0; j < 8; ++j) {
      if (A[j] < NODE_SPLIT) bA |= ((lbm[A[j] >> 5] >> (A[j] & 31)) & 1u) << j;
      if (B[j] < NODE_SPLIT) bB |= ((lbm[B[j] >> 5] >> (B[j] & 31)) & 1u) << j;
    }
  }
  __syncthreads();
  {
    const v4u* src = (const v4u*)(bm + BM_W0);
    for (int j = t; j < (BM_W1 + 3) / 4; j += EB_THREADS)
      ((v4u*)lbm)[j] = src[j];
  }
  __syncthreads();
  if (act) {
#pragma unroll
    for (int j = 0; j < 8; ++j) {
      if (A[j] >= NODE_SPLIT) {
        int q = A[j] - NODE_SPLIT;
        bA |= ((lbm[q >> 5] >> (q & 31)) & 1u) << j;
      }
      if (B[j] >= NODE_SPLIT) {
        int q = B[j] - NODE_SPLIT;
        bB |= ((lbm[q >> 5] >> (q & 31)) & 1u) << j;
      }
    }
    unsigned mm = bA & bB;
    float fa[8], fb[8], fm[8];
#pragma unroll
    for (int j = 0; j < 8; ++j) {
      bool m = (mm >> j) & 1u;
      int na = -1, nb = -1;
      if (m) { na = ni[A[j]]; nb = ni[B[j]]; }
      fa[j] = m ? (float)na : -1.0f;
      fb[j] = m ? (float)nb : -1.0f;
      fm[j] = m ? 1.0f : 0.0f;
    }
    __builtin_nontemporal_store(*(const v4f*)&fa[0], (v4f*)(oedge + e));
    __builtin_nontemporal_store(*(const v4f*)&fa[4], (v4f*)(oedge + e) + 1);
    __builtin_nontemporal_store(*(const v4f*)&fb[0], (v4f*)(oedge + (long long)N_EDGES + e));
    __builtin_nontemporal_store(*(const v4f*)&fb[4], (v4f*)(oedge + (long long)N_EDGES + e) + 1);
    __builtin_nontemporal_store(*(const v4f*)&fm[0], (v4f*)(omask + e));
    __builtin_nontemporal_store(*(const v4f*)&fm[4], (v4f*)(omask + e) + 1);
  }
}

extern "C" void kernel_launch(void* const* d_in, const int* in_sizes, int n_in,
                              void* d_out, int out_size, void* d_ws, size_t ws_size,
                              hipStream_t stream) {
  const float* x  = (const float*)d_in[0];
  const int*   ei = (const int*)d_in[1];
  const float* w  = (const float*)d_in[2];
  float* out = (float*)d_out;

  char* ws = (char*)d_ws;
  size_t off = 0;
  auto alloc = [&](size_t bytes) -> void* {
    void* ptr = ws + off;
    off += (bytes + 255) & ~size_t(255);
    return ptr;
  };
  u64*      kp0    = (u64*)alloc((size_t)N_NODES * 8);
  u64*      kp1    = (u64*)alloc((size_t)N_NODES * 8);
  int*      ni     = (int*)alloc((size_t)N_NODES * 4);
  unsigned* rowsum = (unsigned*)alloc((size_t)NDIG * 4);
  unsigned* histDM0= (unsigned*)alloc((size_t)NDIG * NB * 4);
  // contiguous zero-region: bm | histDM passes 1..3
  char*     zbase  = (char*)alloc(0);
  unsigned* bm     = (unsigned*)alloc((size_t)BM_ALLOC * 4);
  unsigned* histDM1= (unsigned*)alloc((size_t)NDIG * NB * 4);
  unsigned* histDM2= (unsigned*)alloc((size_t)NDIG * NB * 4);
  unsigned* histDM3= (unsigned*)alloc((size_t)NDIG * NB * 4);
  int       zwords = (int)((unsigned*)(histDM3 + NDIG * NB) - (unsigned*)zbase);
  int       z4     = zwords / 4;  // 256B-aligned chunks -> /4 exact
  (void)ws_size; (void)in_sizes; (void)n_in; (void)out_size;

  zero_meta <<<(z4 + 255) / 256, 256, 0, stream>>>((v4u*)zbase, z4);
  score_pass<<<NB, STHREADS, 0, stream>>>(x, w, kp0, histDM0);

  scan_rows<<<NDIG, 512, 0, stream>>>(histDM0, rowsum);
  scatter_pass<0><<<NB, STHREADS, 0, stream>>>(kp0, kp1, histDM0, rowsum, histDM1,
                                               nullptr, nullptr, nullptr, nullptr);
  scan_rows<<<NDIG, 512, 0, stream>>>(histDM1, rowsum);
  scatter_pass<1><<<NB, STHREADS, 0, stream>>>(kp1, kp0, histDM1, rowsum, histDM2,
                                               nullptr, nullptr, nullptr, nullptr);
  scan_rows<<<NDIG, 512, 0, stream>>>(histDM2, rowsum);
  scatter_pass<2><<<NB, STHREADS, 0, stream>>>(kp0, kp1, histDM2, rowsum, histDM3,
                                               nullptr, nullptr, nullptr, nullptr);
  scan_rows<<<NDIG, 512, 0, stream>>>(histDM3, rowsum);
  scatter_pass<3><<<NB, STHREADS, 0, stream>>>(kp1, nullptr, histDM3, rowsum, nullptr,
                                               x, ni, bm, out);

  edge_kernel<<<(N_EDGES + EB_EDGES - 1) / EB_EDGES, EB_THREADS, 0, stream>>>(
      ei, ni, bm, out + 1500000, out + 33500000);
}

// Round 9
// 221.536 us; speedup vs baseline: 2.6162x; 2.6162x over previous
//
#include <hip/hip_runtime.h>

// ---------------------------------------------------------------------------
// TopKPooling (PyG-style) on MI355X.
// score = tanh((x @ w) / ||w||)  [XLA EmitTanh f32 replica — DO NOT TOUCH,
//                                 bit-exactness validated in round 1]
// Stable LSD radix sort, round-3 validated dense structure: per pass
// {standalone hist (LDS atomics, no global atomics), scan_rows, scatter}.
// Global sync strictly via kernel boundaries — lookback (r5), wait-all
// (r6/7) and fused atomic-hist (r8) all measured 3-20x slower: device-scope
// atomic RMW bypasses per-XCD L2 and serializes at the fabric, worst when
// the tanh-score exponent byte concentrates digits onto few cache lines.
// Select fused into final scatter (r6-validated): no init/select kernels.
// Edge relabel: two-phase 64KB LDS bitmap probe + conditional ni gather
// (validated round 3; untouched).
// ---------------------------------------------------------------------------

#define N_NODES 1000000
#define N_EDGES 16000000
#define K_SEL   500000

typedef int      v4i __attribute__((ext_vector_type(4)));
typedef float    v4f __attribute__((ext_vector_type(4)));
typedef unsigned v4u __attribute__((ext_vector_type(4)));
typedef unsigned long long u64;

static constexpr int NDIG     = 256;
static constexpr int STHREADS = 256;                 // 4 waves
static constexpr int SIPT     = 8;
static constexpr int SCHUNK   = STHREADS * SIPT;     // 2048
static constexpr int NB       = (N_NODES + SCHUNK - 1) / SCHUNK;  // 489
static constexpr int NWAVE    = STHREADS / 64;

static constexpr int EB_THREADS = 1024;
static constexpr int EB_EDGES   = EB_THREADS * 8;    // 8192
static constexpr int NODE_SPLIT = 524288;            // word-aligned split
static constexpr int BM_WORDS   = (N_NODES + 31) / 32;   // 31250
static constexpr int BM_W0      = NODE_SPLIT / 32;       // 16384 (64 KiB)
static constexpr int BM_W1      = BM_WORDS - BM_W0;      // 14866
static constexpr int BM_ALLOC   = 31264;                 // padded to x4

// --- XLA EmitTanh f32 replica (elemental_ir_emitter). No FMA contraction. ---
__device__ __forceinline__ float tanh_xla(float x) {
  const float kCutoff = 0.0004f;
  const float kClamp  = 7.90531110763549805f;
  float ax = fabsf(x);
  float xc = fminf(fmaxf(x, -kClamp), kClamp);
  float x2 = __fmul_rn(xc, xc);
  float p = -2.76076847742355e-16f;
  p = __fadd_rn(__fmul_rn(p, x2),  2.00018790482477e-13f);
  p = __fadd_rn(__fmul_rn(p, x2), -8.60467152213735e-11f);
  p = __fadd_rn(__fmul_rn(p, x2),  5.12229709037114e-08f);
  p = __fadd_rn(__fmul_rn(p, x2),  1.48572235717979e-05f);
  p = __fadd_rn(__fmul_rn(p, x2),  6.37261928875436e-04f);
  p = __fadd_rn(__fmul_rn(p, x2),  4.89352455891786e-03f);
  float num = __fmul_rn(xc, p);
  float q = 1.19825839466702e-06f;
  q = __fadd_rn(__fmul_rn(q, x2), 1.18534705686654e-04f);
  q = __fadd_rn(__fmul_rn(q, x2), 2.26843463243900e-03f);
  q = __fadd_rn(__fmul_rn(q, x2), 4.89352518554385e-03f);
  float r = __fdiv_rn(num, q);
  return (ax < kCutoff) ? x : r;
}

// ---- zero the bitmap (125 KiB) with one uint4 per thread ----
__global__ __launch_bounds__(256) void zero_meta(v4u* __restrict__ p, int n4) {
  int i = blockIdx.x * 256 + threadIdx.x;
  if (i < n4) p[i] = v4u{0u, 0u, 0u, 0u};
}

// ---- score + packed keys + exact pass-0 per-block histogram ----
__global__ __launch_bounds__(STHREADS) void score_pass(
    const float* __restrict__ x, const float* __restrict__ w,
    u64* __restrict__ kp0, unsigned* __restrict__ histDM0) {
  __shared__ unsigned h[NDIG];
  const int t = threadIdx.x, b = blockIdx.x;
  const int base = b * SCHUNK;
  h[t] = 0;
  __syncthreads();
  float w0 = w[0], w1 = w[1], w2 = w[2];
  float nrm = __fsqrt_rn(__fadd_rn(__fadd_rn(__fmul_rn(w0, w0), __fmul_rn(w1, w1)),
                                   __fmul_rn(w2, w2)));
#pragma unroll
  for (int s = 0; s < SIPT; ++s) {
    int i = base + s * STHREADS + t;
    if (i < N_NODES) {
      float dot = __fadd_rn(__fadd_rn(__fmul_rn(x[3*i+0], w0), __fmul_rn(x[3*i+1], w1)),
                            __fmul_rn(x[3*i+2], w2));
      float z = __fdiv_rn(dot, nrm);
      float sc = tanh_xla(z);
      unsigned u = __float_as_uint(sc);
      if (u == 0x80000000u) u = 0u;                    // -0 == +0
      u = (u & 0x80000000u) ? ~u : (u | 0x80000000u);  // ascending map
      unsigned key = ~u;                               // descending score
      kp0[i] = ((u64)key << 32) | (unsigned)i;
      atomicAdd(&h[key & 255u], 1u);
    }
  }
  __syncthreads();
  histDM0[t * NB + b] = h[t];
}

// ---- per-block digit histogram of current key array (LDS atomics only) ----
__global__ void radix_hist(const u64* __restrict__ kp,
                           unsigned* __restrict__ histDM, int shift) {
  __shared__ unsigned h[NDIG];
  int t = threadIdx.x;  // 256 threads == NDIG
  h[t] = 0;
  __syncthreads();
  int base = blockIdx.x * SCHUNK;
#pragma unroll
  for (int it = 0; it < SCHUNK / 256; ++it) {
    int i = base + it * 256 + t;
    if (i < N_NODES) atomicAdd(&h[(unsigned)(kp[i] >> shift) & 255u], 1u);
  }
  __syncthreads();
  histDM[t * NB + blockIdx.x] = h[t];
}

// ---- exclusive scan of each digit row (NB entries); rowsum[d] = total ----
__global__ void scan_rows(unsigned* __restrict__ histDM, unsigned* __restrict__ rowsum) {
  __shared__ unsigned lds[512];
  int d = blockIdx.x, t = threadIdx.x;
  unsigned v = (t < NB) ? histDM[d * NB + t] : 0u;
  lds[t] = v;
  __syncthreads();
#pragma unroll
  for (int off = 1; off < 512; off <<= 1) {
    unsigned add = (t >= off) ? lds[t - off] : 0u;
    __syncthreads();
    lds[t] += add;
    __syncthreads();
  }
  if (t < NB) histDM[d * NB + t] = lds[t] - v;
  if (t == 511) rowsum[d] = lds[511];
}

// ---- stable scatter (r3-validated core): ballot ranks + LDS reorder;
// rowbase scan folded per block. PASS==3 fused with select.
template <int PASS>
__global__ __launch_bounds__(STHREADS) void scatter_pass(
    const u64* __restrict__ kin, u64* __restrict__ kout,
    const unsigned* __restrict__ histDM, const unsigned* __restrict__ rowsum,
    const float* __restrict__ x, int* __restrict__ ni,
    unsigned* __restrict__ bm, float* __restrict__ xout) {
  constexpr bool FINAL = (PASS == 3);
  __shared__ unsigned short whist[SIPT][NWAVE][NDIG];  // 16 KiB
  __shared__ unsigned goff[NDIG];
  __shared__ unsigned bexcl[NDIG];
  __shared__ unsigned scanbuf[NDIG];
  __shared__ u64 lkp[FINAL ? 1 : SCHUNK];              // 16 KiB (non-final)
  const int t = threadIdx.x, b = blockIdx.x;
  const int wave = t >> 6, lane = t & 63;
  const int base = b * SCHUNK;
  const int sh = 32 + 8 * PASS;

  for (int j = t; j < SIPT * NWAVE * NDIG; j += STHREADS)
    ((unsigned short*)whist)[j] = 0;
  // rowbase = exclusive scan of rowsum (256 entries, folded per block — r3)
  unsigned rs = rowsum[t];
  scanbuf[t] = rs;
  __syncthreads();
#pragma unroll
  for (int o = 1; o < NDIG; o <<= 1) {
    unsigned add = (t >= o) ? scanbuf[t - o] : 0u;
    __syncthreads();
    scanbuf[t] += add;
    __syncthreads();
  }
  goff[t] = (scanbuf[t] - rs) + histDM[t * NB + b];
  __syncthreads();

  u64 k[SIPT];
  unsigned dg[SIPT], lr[SIPT];
  bool val[SIPT];
#pragma unroll
  for (int s = 0; s < SIPT; ++s) {
    int i = base + s * STHREADS + t;
    val[s] = (i < N_NODES);
    k[s] = val[s] ? kin[i] : 0ull;
    dg[s] = (unsigned)(k[s] >> sh) & 255u;
  }
#pragma unroll
  for (int s = 0; s < SIPT; ++s) {
    unsigned long long m = ~0ull;
#pragma unroll
    for (int bb = 0; bb < 8; ++bb) {
      unsigned long long vote = __ballot((dg[s] >> bb) & 1u);
      m &= ((dg[s] >> bb) & 1u) ? vote : ~vote;
    }
    m &= __ballot(val[s]);
    lr[s] = (unsigned)__popcll(m & ((1ull << lane) - 1ull));
    if (val[s] && lr[s] == 0)  // leader: lowest valid lane of its digit group
      whist[s][wave][dg[s]] = (unsigned short)__popcll(m);
  }
  __syncthreads();
  // per-digit serial scan over (s,wave) in item order; run = block digit count
  unsigned run = 0;
#pragma unroll
  for (int s = 0; s < SIPT; ++s)
#pragma unroll
    for (int wv = 0; wv < NWAVE; ++wv) {
      unsigned c = whist[s][wv][t];
      whist[s][wv][t] = (unsigned short)run;
      run += c;
    }
  scanbuf[t] = run;
  __syncthreads();
#pragma unroll
  for (int o = 1; o < NDIG; o <<= 1) {
    unsigned add = (t >= o) ? scanbuf[t - o] : 0u;
    __syncthreads();
    scanbuf[t] += add;
    __syncthreads();
  }
  bexcl[t] = scanbuf[t] - run;
  __syncthreads();

  if constexpr (!FINAL) {
    // local counting-sort reorder into LDS
#pragma unroll
    for (int s = 0; s < SIPT; ++s)
      if (val[s]) {
        unsigned lp = bexcl[dg[s]] + (unsigned)whist[s][wave][dg[s]] + lr[s];
        lkp[lp] = k[s];
      }
    __syncthreads();
    // contiguous LDS read -> digit-run-coalesced global write
    int nvalid = min(N_NODES - base, SCHUNK);
#pragma unroll
    for (int s = 0; s < SIPT; ++s) {
      int j = s * STHREADS + t;
      if (j < nvalid) {
        u64 kk = lkp[j];
        unsigned d = (unsigned)(kk >> sh) & 255u;
        kout[goff[d] + ((unsigned)j - bexcl[d])] = kk;
      }
    }
  } else {
    // fused select: position < K_SEL -> emit ni/bm/xout directly
#pragma unroll
    for (int s = 0; s < SIPT; ++s) {
      if (val[s]) {
        unsigned gpos = goff[dg[s]] + (unsigned)whist[s][wave][dg[s]] + lr[s];
        if (gpos < K_SEL) {
          int idx = (int)(unsigned)(k[s] & 0xFFFFFFFFull);
          ni[idx] = (int)gpos;
          atomicOr(&bm[idx >> 5], 1u << (idx & 31));
          unsigned uo = ~(unsigned)(k[s] >> 32);          // invert key bijection
          unsigned bits = (uo & 0x80000000u) ? (uo ^ 0x80000000u) : ~uo;
          float sc = __uint_as_float(bits);
          xout[3*gpos+0] = __fmul_rn(x[3*idx+0], sc);
          xout[3*gpos+1] = __fmul_rn(x[3*idx+1], sc);
          xout[3*gpos+2] = __fmul_rn(x[3*idx+2], sc);
        }
      }
    }
  }
}

// ---- edge relabel: two-phase 64KB LDS bitmap (validated round 3) ----
__global__ __launch_bounds__(EB_THREADS) void edge_kernel(
    const int* __restrict__ ei, const int* __restrict__ ni,
    const unsigned* __restrict__ bm,
    float* __restrict__ oedge, float* __restrict__ omask) {
  __shared__ unsigned lbm[BM_W0];  // 64 KiB
  int t = threadIdx.x;
  long long e = (long long)blockIdx.x * EB_EDGES + (long long)t * 8;
  bool act = (e + 8 <= (long long)N_EDGES);

  v4i a0{}, a1{}, b0{}, b1{};
  if (act) {
    a0 = __builtin_nontemporal_load((const v4i*)(ei + e));
    a1 = __builtin_nontemporal_load((const v4i*)(ei + e) + 1);
    b0 = __builtin_nontemporal_load((const v4i*)(ei + (long long)N_EDGES + e));
    b1 = __builtin_nontemporal_load((const v4i*)(ei + (long long)N_EDGES + e) + 1);
  }
  int A[8], B[8];
#pragma unroll
  for (int j = 0; j < 4; ++j) {
    A[j] = a0[j]; A[4 + j] = a1[j];
    B[j] = b0[j]; B[4 + j] = b1[j];
  }
#pragma unroll
  for (int j = 0; j < BM_W0 / (EB_THREADS * 4); ++j)
    ((v4u*)lbm)[t + j * EB_THREADS] = ((const v4u*)bm)[t + j * EB_THREADS];
  __syncthreads();
  unsigned bA = 0, bB = 0;
  if (act) {
#pragma unroll
    for (int j = 0; j < 8; ++j) {
      if (A[j] < NODE_SPLIT) bA |= ((lbm[A[j] >> 5] >> (A[j] & 31)) & 1u) << j;
      if (B[j] < NODE_SPLIT) bB |= ((lbm[B[j] >> 5] >> (B[j] & 31)) & 1u) << j;
    }
  }
  __syncthreads();
  {
    const v4u* src = (const v4u*)(bm + BM_W0);
    for (int j = t; j < (BM_W1 + 3) / 4; j += EB_THREADS)
      ((v4u*)lbm)[j] = src[j];
  }
  __syncthreads();
  if (act) {
#pragma unroll
    for (int j = 0; j < 8; ++j) {
      if (A[j] >= NODE_SPLIT) {
        int q = A[j] - NODE_SPLIT;
        bA |= ((lbm[q >> 5] >> (q & 31)) & 1u) << j;
      }
      if (B[j] >= NODE_SPLIT) {
        int q = B[j] - NODE_SPLIT;
        bB |= ((lbm[q >> 5] >> (q & 31)) & 1u) << j;
      }
    }
    unsigned mm = bA & bB;
    float fa[8], fb[8], fm[8];
#pragma unroll
    for (int j = 0; j < 8; ++j) {
      bool m = (mm >> j) & 1u;
      int na = -1, nb = -1;
      if (m) { na = ni[A[j]]; nb = ni[B[j]]; }
      fa[j] = m ? (float)na : -1.0f;
      fb[j] = m ? (float)nb : -1.0f;
      fm[j] = m ? 1.0f : 0.0f;
    }
    __builtin_nontemporal_store(*(const v4f*)&fa[0], (v4f*)(oedge + e));
    __builtin_nontemporal_store(*(const v4f*)&fa[4], (v4f*)(oedge + e) + 1);
    __builtin_nontemporal_store(*(const v4f*)&fb[0], (v4f*)(oedge + (long long)N_EDGES + e));
    __builtin_nontemporal_store(*(const v4f*)&fb[4], (v4f*)(oedge + (long long)N_EDGES + e) + 1);
    __builtin_nontemporal_store(*(const v4f*)&fm[0], (v4f*)(omask + e));
    __builtin_nontemporal_store(*(const v4f*)&fm[4], (v4f*)(omask + e) + 1);
  }
}

extern "C" void kernel_launch(void* const* d_in, const int* in_sizes, int n_in,
                              void* d_out, int out_size, void* d_ws, size_t ws_size,
                              hipStream_t stream) {
  const float* x  = (const float*)d_in[0];
  const int*   ei = (const int*)d_in[1];
  const float* w  = (const float*)d_in[2];
  float* out = (float*)d_out;

  char* ws = (char*)d_ws;
  size_t off = 0;
  auto alloc = [&](size_t bytes) -> void* {
    void* ptr = ws + off;
    off += (bytes + 255) & ~size_t(255);
    return ptr;
  };
  u64*      kp0    = (u64*)alloc((size_t)N_NODES * 8);
  u64*      kp1    = (u64*)alloc((size_t)N_NODES * 8);
  int*      ni     = (int*)alloc((size_t)N_NODES * 4);
  unsigned* rowsum = (unsigned*)alloc((size_t)NDIG * 4);
  unsigned* histDM0= (unsigned*)alloc((size_t)NDIG * NB * 4);
  unsigned* histDM1= (unsigned*)alloc((size_t)NDIG * NB * 4);
  unsigned* histDM2= (unsigned*)alloc((size_t)NDIG * NB * 4);
  unsigned* histDM3= (unsigned*)alloc((size_t)NDIG * NB * 4);
  unsigned* bm     = (unsigned*)alloc((size_t)BM_ALLOC * 4);
  (void)ws_size; (void)in_sizes; (void)n_in; (void)out_size;

  zero_meta <<<(BM_ALLOC / 4 + 255) / 256, 256, 0, stream>>>((v4u*)bm, BM_ALLOC / 4);
  score_pass<<<NB, STHREADS, 0, stream>>>(x, w, kp0, histDM0);

  scan_rows<<<NDIG, 512, 0, stream>>>(histDM0, rowsum);
  scatter_pass<0><<<NB, STHREADS, 0, stream>>>(kp0, kp1, histDM0, rowsum,
                                               nullptr, nullptr, nullptr, nullptr);
  radix_hist<<<NB, 256, 0, stream>>>(kp1, histDM1, 40);
  scan_rows<<<NDIG, 512, 0, stream>>>(histDM1, rowsum);
  scatter_pass<1><<<NB, STHREADS, 0, stream>>>(kp1, kp0, histDM1, rowsum,
                                               nullptr, nullptr, nullptr, nullptr);
  radix_hist<<<NB, 256, 0, stream>>>(kp0, histDM2, 48);
  scan_rows<<<NDIG, 512, 0, stream>>>(histDM2, rowsum);
  scatter_pass<2><<<NB, STHREADS, 0, stream>>>(kp0, kp1, histDM2, rowsum,
                                               nullptr, nullptr, nullptr, nullptr);
  radix_hist<<<NB, 256, 0, stream>>>(kp1, histDM3, 56);
  scan_rows<<<NDIG, 512, 0, stream>>>(histDM3, rowsum);
  scatter_pass<3><<<NB, STHREADS, 0, stream>>>(kp1, nullptr, histDM3, rowsum,
                                               x, ni, bm, out);

  edge_kernel<<<(N_EDGES + EB_EDGES - 1) / EB_EDGES, EB_THREADS, 0, stream>>>(
      ei, ni, bm, out + 1500000, out + 33500000);
}

// Round 10
// 212.420 us; speedup vs baseline: 2.7284x; 1.0429x over previous
//
#include <hip/hip_runtime.h>

// ---------------------------------------------------------------------------
// TopKPooling (PyG-style) on MI355X.
// score = tanh((x @ w) / ||w||)  [XLA EmitTanh f32 replica — DO NOT TOUCH,
//                                 bit-exactness validated in round 1]
// Stable LSD radix sort, round-3 validated dense structure: per pass
// {standalone hist (LDS atomics, no global atomics), scan_rows, scatter}.
// Global sync strictly via kernel boundaries — lookback (r5), wait-all
// (r6/7) and fused atomic-hist (r8) all measured 3-20x slower: device-scope
// atomic RMW bypasses per-XCD L2 and serializes at the fabric.
// Select fused into final scatter (r6-validated): no init/select kernels.
// Edge relabel: two-phase 64KB LDS bitmap probe + conditional ni gather.
// r10 change: ei loads are CACHED (not nt) — ei (128MB) fits the 256MB L3
// and is re-read every graph replay; r9 counters showed partial L3 hits
// despite nt. Stores stay nt so 192MB of output doesn't evict ei from L3.
// ---------------------------------------------------------------------------

#define N_NODES 1000000
#define N_EDGES 16000000
#define K_SEL   500000

typedef int      v4i __attribute__((ext_vector_type(4)));
typedef float    v4f __attribute__((ext_vector_type(4)));
typedef unsigned v4u __attribute__((ext_vector_type(4)));
typedef unsigned long long u64;

static constexpr int NDIG     = 256;
static constexpr int STHREADS = 256;                 // 4 waves
static constexpr int SIPT     = 8;
static constexpr int SCHUNK   = STHREADS * SIPT;     // 2048
static constexpr int NB       = (N_NODES + SCHUNK - 1) / SCHUNK;  // 489
static constexpr int NWAVE    = STHREADS / 64;

static constexpr int EB_THREADS = 1024;
static constexpr int EB_EDGES   = EB_THREADS * 8;    // 8192
static constexpr int NODE_SPLIT = 524288;            // word-aligned split
static constexpr int BM_WORDS   = (N_NODES + 31) / 32;   // 31250
static constexpr int BM_W0      = NODE_SPLIT / 32;       // 16384 (64 KiB)
static constexpr int BM_W1      = BM_WORDS - BM_W0;      // 14866
static constexpr int BM_ALLOC   = 31264;                 // padded to x4

// --- XLA EmitTanh f32 replica (elemental_ir_emitter). No FMA contraction. ---
__device__ __forceinline__ float tanh_xla(float x) {
  const float kCutoff = 0.0004f;
  const float kClamp  = 7.90531110763549805f;
  float ax = fabsf(x);
  float xc = fminf(fmaxf(x, -kClamp), kClamp);
  float x2 = __fmul_rn(xc, xc);
  float p = -2.76076847742355e-16f;
  p = __fadd_rn(__fmul_rn(p, x2),  2.00018790482477e-13f);
  p = __fadd_rn(__fmul_rn(p, x2), -8.60467152213735e-11f);
  p = __fadd_rn(__fmul_rn(p, x2),  5.12229709037114e-08f);
  p = __fadd_rn(__fmul_rn(p, x2),  1.48572235717979e-05f);
  p = __fadd_rn(__fmul_rn(p, x2),  6.37261928875436e-04f);
  p = __fadd_rn(__fmul_rn(p, x2),  4.89352455891786e-03f);
  float num = __fmul_rn(xc, p);
  float q = 1.19825839466702e-06f;
  q = __fadd_rn(__fmul_rn(q, x2), 1.18534705686654e-04f);
  q = __fadd_rn(__fmul_rn(q, x2), 2.26843463243900e-03f);
  q = __fadd_rn(__fmul_rn(q, x2), 4.89352518554385e-03f);
  float r = __fdiv_rn(num, q);
  return (ax < kCutoff) ? x : r;
}

// ---- zero the bitmap (125 KiB) with one uint4 per thread ----
__global__ __launch_bounds__(256) void zero_meta(v4u* __restrict__ p, int n4) {
  int i = blockIdx.x * 256 + threadIdx.x;
  if (i < n4) p[i] = v4u{0u, 0u, 0u, 0u};
}

// ---- score + packed keys + exact pass-0 per-block histogram ----
__global__ __launch_bounds__(STHREADS) void score_pass(
    const float* __restrict__ x, const float* __restrict__ w,
    u64* __restrict__ kp0, unsigned* __restrict__ histDM0) {
  __shared__ unsigned h[NDIG];
  const int t = threadIdx.x, b = blockIdx.x;
  const int base = b * SCHUNK;
  h[t] = 0;
  __syncthreads();
  float w0 = w[0], w1 = w[1], w2 = w[2];
  float nrm = __fsqrt_rn(__fadd_rn(__fadd_rn(__fmul_rn(w0, w0), __fmul_rn(w1, w1)),
                                   __fmul_rn(w2, w2)));
#pragma unroll
  for (int s = 0; s < SIPT; ++s) {
    int i = base + s * STHREADS + t;
    if (i < N_NODES) {
      float dot = __fadd_rn(__fadd_rn(__fmul_rn(x[3*i+0], w0), __fmul_rn(x[3*i+1], w1)),
                            __fmul_rn(x[3*i+2], w2));
      float z = __fdiv_rn(dot, nrm);
      float sc = tanh_xla(z);
      unsigned u = __float_as_uint(sc);
      if (u == 0x80000000u) u = 0u;                    // -0 == +0
      u = (u & 0x80000000u) ? ~u : (u | 0x80000000u);  // ascending map
      unsigned key = ~u;                               // descending score
      kp0[i] = ((u64)key << 32) | (unsigned)i;
      atomicAdd(&h[key & 255u], 1u);
    }
  }
  __syncthreads();
  histDM0[t * NB + b] = h[t];
}

// ---- per-block digit histogram of current key array (LDS atomics only) ----
__global__ void radix_hist(const u64* __restrict__ kp,
                           unsigned* __restrict__ histDM, int shift) {
  __shared__ unsigned h[NDIG];
  int t = threadIdx.x;  // 256 threads == NDIG
  h[t] = 0;
  __syncthreads();
  int base = blockIdx.x * SCHUNK;
#pragma unroll
  for (int it = 0; it < SCHUNK / 256; ++it) {
    int i = base + it * 256 + t;
    if (i < N_NODES) atomicAdd(&h[(unsigned)(kp[i] >> shift) & 255u], 1u);
  }
  __syncthreads();
  histDM[t * NB + blockIdx.x] = h[t];
}

// ---- exclusive scan of each digit row (NB entries); rowsum[d] = total ----
__global__ void scan_rows(unsigned* __restrict__ histDM, unsigned* __restrict__ rowsum) {
  __shared__ unsigned lds[512];
  int d = blockIdx.x, t = threadIdx.x;
  unsigned v = (t < NB) ? histDM[d * NB + t] : 0u;
  lds[t] = v;
  __syncthreads();
#pragma unroll
  for (int off = 1; off < 512; off <<= 1) {
    unsigned add = (t >= off) ? lds[t - off] : 0u;
    __syncthreads();
    lds[t] += add;
    __syncthreads();
  }
  if (t < NB) histDM[d * NB + t] = lds[t] - v;
  if (t == 511) rowsum[d] = lds[511];
}

// ---- stable scatter (r3-validated core): ballot ranks + LDS reorder;
// rowbase scan folded per block. PASS==3 fused with select.
template <int PASS>
__global__ __launch_bounds__(STHREADS) void scatter_pass(
    const u64* __restrict__ kin, u64* __restrict__ kout,
    const unsigned* __restrict__ histDM, const unsigned* __restrict__ rowsum,
    const float* __restrict__ x, int* __restrict__ ni,
    unsigned* __restrict__ bm, float* __restrict__ xout) {
  constexpr bool FINAL = (PASS == 3);
  __shared__ unsigned short whist[SIPT][NWAVE][NDIG];  // 16 KiB
  __shared__ unsigned goff[NDIG];
  __shared__ unsigned bexcl[NDIG];
  __shared__ unsigned scanbuf[NDIG];
  __shared__ u64 lkp[FINAL ? 1 : SCHUNK];              // 16 KiB (non-final)
  const int t = threadIdx.x, b = blockIdx.x;
  const int wave = t >> 6, lane = t & 63;
  const int base = b * SCHUNK;
  const int sh = 32 + 8 * PASS;

  for (int j = t; j < SIPT * NWAVE * NDIG; j += STHREADS)
    ((unsigned short*)whist)[j] = 0;
  // rowbase = exclusive scan of rowsum (256 entries, folded per block — r3)
  unsigned rs = rowsum[t];
  scanbuf[t] = rs;
  __syncthreads();
#pragma unroll
  for (int o = 1; o < NDIG; o <<= 1) {
    unsigned add = (t >= o) ? scanbuf[t - o] : 0u;
    __syncthreads();
    scanbuf[t] += add;
    __syncthreads();
  }
  goff[t] = (scanbuf[t] - rs) + histDM[t * NB + b];
  __syncthreads();

  u64 k[SIPT];
  unsigned dg[SIPT], lr[SIPT];
  bool val[SIPT];
#pragma unroll
  for (int s = 0; s < SIPT; ++s) {
    int i = base + s * STHREADS + t;
    val[s] = (i < N_NODES);
    k[s] = val[s] ? kin[i] : 0ull;
    dg[s] = (unsigned)(k[s] >> sh) & 255u;
  }
#pragma unroll
  for (int s = 0; s < SIPT; ++s) {
    unsigned long long m = ~0ull;
#pragma unroll
    for (int bb = 0; bb < 8; ++bb) {
      unsigned long long vote = __ballot((dg[s] >> bb) & 1u);
      m &= ((dg[s] >> bb) & 1u) ? vote : ~vote;
    }
    m &= __ballot(val[s]);
    lr[s] = (unsigned)__popcll(m & ((1ull << lane) - 1ull));
    if (val[s] && lr[s] == 0)  // leader: lowest valid lane of its digit group
      whist[s][wave][dg[s]] = (unsigned short)__popcll(m);
  }
  __syncthreads();
  // per-digit serial scan over (s,wave) in item order; run = block digit count
  unsigned run = 0;
#pragma unroll
  for (int s = 0; s < SIPT; ++s)
#pragma unroll
    for (int wv = 0; wv < NWAVE; ++wv) {
      unsigned c = whist[s][wv][t];
      whist[s][wv][t] = (unsigned short)run;
      run += c;
    }
  scanbuf[t] = run;
  __syncthreads();
#pragma unroll
  for (int o = 1; o < NDIG; o <<= 1) {
    unsigned add = (t >= o) ? scanbuf[t - o] : 0u;
    __syncthreads();
    scanbuf[t] += add;
    __syncthreads();
  }
  bexcl[t] = scanbuf[t] - run;
  __syncthreads();

  if constexpr (!FINAL) {
    // local counting-sort reorder into LDS
#pragma unroll
    for (int s = 0; s < SIPT; ++s)
      if (val[s]) {
        unsigned lp = bexcl[dg[s]] + (unsigned)whist[s][wave][dg[s]] + lr[s];
        lkp[lp] = k[s];
      }
    __syncthreads();
    // contiguous LDS read -> digit-run-coalesced global write
    int nvalid = min(N_NODES - base, SCHUNK);
#pragma unroll
    for (int s = 0; s < SIPT; ++s) {
      int j = s * STHREADS + t;
      if (j < nvalid) {
        u64 kk = lkp[j];
        unsigned d = (unsigned)(kk >> sh) & 255u;
        kout[goff[d] + ((unsigned)j - bexcl[d])] = kk;
      }
    }
  } else {
    // fused select: position < K_SEL -> emit ni/bm/xout directly
#pragma unroll
    for (int s = 0; s < SIPT; ++s) {
      if (val[s]) {
        unsigned gpos = goff[dg[s]] + (unsigned)whist[s][wave][dg[s]] + lr[s];
        if (gpos < K_SEL) {
          int idx = (int)(unsigned)(k[s] & 0xFFFFFFFFull);
          ni[idx] = (int)gpos;
          atomicOr(&bm[idx >> 5], 1u << (idx & 31));
          unsigned uo = ~(unsigned)(k[s] >> 32);          // invert key bijection
          unsigned bits = (uo & 0x80000000u) ? (uo ^ 0x80000000u) : ~uo;
          float sc = __uint_as_float(bits);
          xout[3*gpos+0] = __fmul_rn(x[3*idx+0], sc);
          xout[3*gpos+1] = __fmul_rn(x[3*idx+1], sc);
          xout[3*gpos+2] = __fmul_rn(x[3*idx+2], sc);
        }
      }
    }
  }
}

// ---- edge relabel: two-phase 64KB LDS bitmap; ei loads cached (L3) ----
__global__ __launch_bounds__(EB_THREADS) void edge_kernel(
    const int* __restrict__ ei, const int* __restrict__ ni,
    const unsigned* __restrict__ bm,
    float* __restrict__ oedge, float* __restrict__ omask) {
  __shared__ unsigned lbm[BM_W0];  // 64 KiB
  int t = threadIdx.x;
  long long e = (long long)blockIdx.x * EB_EDGES + (long long)t * 8;
  bool act = (e + 8 <= (long long)N_EDGES);

  v4i a0{}, a1{}, b0{}, b1{};
  if (act) {
    // cached loads: ei (128MB) stays L3-resident across graph replays
    a0 = *(const v4i*)(ei + e);
    a1 = *((const v4i*)(ei + e) + 1);
    b0 = *(const v4i*)(ei + (long long)N_EDGES + e);
    b1 = *((const v4i*)(ei + (long long)N_EDGES + e) + 1);
  }
  int A[8], B[8];
#pragma unroll
  for (int j = 0; j < 4; ++j) {
    A[j] = a0[j]; A[4 + j] = a1[j];
    B[j] = b0[j]; B[4 + j] = b1[j];
  }
#pragma unroll
  for (int j = 0; j < BM_W0 / (EB_THREADS * 4); ++j)
    ((v4u*)lbm)[t + j * EB_THREADS] = ((const v4u*)bm)[t + j * EB_THREADS];
  __syncthreads();
  unsigned bA = 0, bB = 0;
  if (act) {
#pragma unroll
    for (int j = 0; j < 8; ++j) {
      if (A[j] < NODE_SPLIT) bA |= ((lbm[A[j] >> 5] >> (A[j] & 31)) & 1u) << j;
      if (B[j] < NODE_SPLIT) bB |= ((lbm[B[j] >> 5] >> (B[j] & 31)) & 1u) << j;
    }
  }
  __syncthreads();
  {
    const v4u* src = (const v4u*)(bm + BM_W0);
    for (int j = t; j < (BM_W1 + 3) / 4; j += EB_THREADS)
      ((v4u*)lbm)[j] = src[j];
  }
  __syncthreads();
  if (act) {
#pragma unroll
    for (int j = 0; j < 8; ++j) {
      if (A[j] >= NODE_SPLIT) {
        int q = A[j] - NODE_SPLIT;
        bA |= ((lbm[q >> 5] >> (q & 31)) & 1u) << j;
      }
      if (B[j] >= NODE_SPLIT) {
        int q = B[j] - NODE_SPLIT;
        bB |= ((lbm[q >> 5] >> (q & 31)) & 1u) << j;
      }
    }
    unsigned mm = bA & bB;
    float fa[8], fb[8], fm[8];
#pragma unroll
    for (int j = 0; j < 8; ++j) {
      bool m = (mm >> j) & 1u;
      int na = -1, nb = -1;
      if (m) { na = ni[A[j]]; nb = ni[B[j]]; }
      fa[j] = m ? (float)na : -1.0f;
      fb[j] = m ? (float)nb : -1.0f;
      fm[j] = m ? 1.0f : 0.0f;
    }
    // nt stores: 192MB of output must NOT allocate in L3 (would evict ei)
    __builtin_nontemporal_store(*(const v4f*)&fa[0], (v4f*)(oedge + e));
    __builtin_nontemporal_store(*(const v4f*)&fa[4], (v4f*)(oedge + e) + 1);
    __builtin_nontemporal_store(*(const v4f*)&fb[0], (v4f*)(oedge + (long long)N_EDGES + e));
    __builtin_nontemporal_store(*(const v4f*)&fb[4], (v4f*)(oedge + (long long)N_EDGES + e) + 1);
    __builtin_nontemporal_store(*(const v4f*)&fm[0], (v4f*)(omask + e));
    __builtin_nontemporal_store(*(const v4f*)&fm[4], (v4f*)(omask + e) + 1);
  }
}

extern "C" void kernel_launch(void* const* d_in, const int* in_sizes, int n_in,
                              void* d_out, int out_size, void* d_ws, size_t ws_size,
                              hipStream_t stream) {
  const float* x  = (const float*)d_in[0];
  const int*   ei = (const int*)d_in[1];
  const float* w  = (const float*)d_in[2];
  float* out = (float*)d_out;

  char* ws = (char*)d_ws;
  size_t off = 0;
  auto alloc = [&](size_t bytes) -> void* {
    void* ptr = ws + off;
    off += (bytes + 255) & ~size_t(255);
    return ptr;
  };
  u64*      kp0    = (u64*)alloc((size_t)N_NODES * 8);
  u64*      kp1    = (u64*)alloc((size_t)N_NODES * 8);
  int*      ni     = (int*)alloc((size_t)N_NODES * 4);
  unsigned* rowsum = (unsigned*)alloc((size_t)NDIG * 4);
  unsigned* histDM0= (unsigned*)alloc((size_t)NDIG * NB * 4);
  unsigned* histDM1= (unsigned*)alloc((size_t)NDIG * NB * 4);
  unsigned* histDM2= (unsigned*)alloc((size_t)NDIG * NB * 4);
  unsigned* histDM3= (unsigned*)alloc((size_t)NDIG * NB * 4);
  unsigned* bm     = (unsigned*)alloc((size_t)BM_ALLOC * 4);
  (void)ws_size; (void)in_sizes; (void)n_in; (void)out_size;

  zero_meta <<<(BM_ALLOC / 4 + 255) / 256, 256, 0, stream>>>((v4u*)bm, BM_ALLOC / 4);
  score_pass<<<NB, STHREADS, 0, stream>>>(x, w, kp0, histDM0);

  scan_rows<<<NDIG, 512, 0, stream>>>(histDM0, rowsum);
  scatter_pass<0><<<NB, STHREADS, 0, stream>>>(kp0, kp1, histDM0, rowsum,
                                               nullptr, nullptr, nullptr, nullptr);
  radix_hist<<<NB, 256, 0, stream>>>(kp1, histDM1, 40);
  scan_rows<<<NDIG, 512, 0, stream>>>(histDM1, rowsum);
  scatter_pass<1><<<NB, STHREADS, 0, stream>>>(kp1, kp0, histDM1, rowsum,
                                               nullptr, nullptr, nullptr, nullptr);
  radix_hist<<<NB, 256, 0, stream>>>(kp0, histDM2, 48);
  scan_rows<<<NDIG, 512, 0, stream>>>(histDM2, rowsum);
  scatter_pass<2><<<NB, STHREADS, 0, stream>>>(kp0, kp1, histDM2, rowsum,
                                               nullptr, nullptr, nullptr, nullptr);
  radix_hist<<<NB, 256, 0, stream>>>(kp1, histDM3, 56);
  scan_rows<<<NDIG, 512, 0, stream>>>(histDM3, rowsum);
  scatter_pass<3><<<NB, STHREADS, 0, stream>>>(kp1, nullptr, histDM3, rowsum,
                                               x, ni, bm, out);

  edge_kernel<<<(N_EDGES + EB_EDGES - 1) / EB_EDGES, EB_THREADS, 0, stream>>>(
      ei, ni, bm, out + 1500000, out + 33500000);
}